// Round 10
// baseline (419.654 us; speedup 1.0000x reference)
//
#include <hip/hip_runtime.h>
#include <hip/hip_bf16.h>

#define FDIM 128
#define HDIM 128
#define ADIM 32
#define BSH 6        // bucket shift: 64 dst nodes per bucket
#define BWD 64
#define CHUNK 8192   // edges per binning block
#define MAXNB 2048   // max buckets supported (N <= 131072)
#define CSRCAP 2048  // padded col capacity per bucket (mean ~1248 @pad8, >16 sigma)

// Storage permutation for T'/H rows: byte position p holds col c(p).
// p = m15*8 + nt  <->  col = nt*16 + m15 ;  c(p) = ((p&7)<<4) | (p>>3)
#define CP(p) ((((p) & 7) << 4) | ((p) >> 3))

typedef short v8s __attribute__((ext_vector_type(8)));
typedef float v4f __attribute__((ext_vector_type(4)));
typedef float v2f __attribute__((ext_vector_type(2)));

// bf16x2 helpers (bitwise; bf16->fp32 exact, fp32->bf16 RNE)
static __device__ __forceinline__ float bflo(unsigned int u) {
    return __builtin_bit_cast(float, u << 16);
}
static __device__ __forceinline__ float bfhi(unsigned int u) {
    return __builtin_bit_cast(float, u & 0xffff0000u);
}
static __device__ __forceinline__ unsigned int bfpack(float a, float b) {
    unsigned int ua = __builtin_bit_cast(unsigned int, a);
    unsigned int ub = __builtin_bit_cast(unsigned int, b);
    ua += 0x7fffu + ((ua >> 16) & 1u);
    ub += 0x7fffu + ((ub >> 16) & 1u);
    return (ua >> 16) | (ub & 0xffff0000u);
}

// ---------------------------------------------------------------------------
// fp8 e4m3 (OCP) helpers. HW path: gfx950 cvt instructions.
#if defined(__has_builtin) && __has_builtin(__builtin_amdgcn_cvt_pk_f32_fp8) && \
    __has_builtin(__builtin_amdgcn_cvt_pk_fp8_f32)
#define FP8_HW 1
#endif

static __device__ __forceinline__ v2f fp8_dec_lo(unsigned int u) {
#ifdef FP8_HW
    return __builtin_amdgcn_cvt_pk_f32_fp8(u, false);
#else
    v2f r;
    #pragma unroll
    for (int i = 0; i < 2; ++i) {
        unsigned b = (u >> (8 * i)) & 0xffu;
        unsigned s = b >> 7, e = (b >> 3) & 0xfu, m = b & 7u;
        float v = (e == 0) ? (float)m * 0.001953125f
                           : __builtin_bit_cast(float, ((e + 120u) << 23) | (m << 20));
        r[i] = s ? -v : v;
    }
    return r;
#endif
}
static __device__ __forceinline__ v2f fp8_dec_hi(unsigned int u) {
#ifdef FP8_HW
    return __builtin_amdgcn_cvt_pk_f32_fp8(u, true);
#else
    return fp8_dec_lo(u >> 16);
#endif
}

#ifndef FP8_HW
static __device__ __forceinline__ unsigned int fp8_enc1(float x) {
    unsigned s = __builtin_bit_cast(unsigned, x) >> 31;
    float ax = fabsf(x);
    if (ax > 448.f) return (s << 7) | 0x7Eu;
    if (ax < 0.0009765625f) return s << 7;
    int e2 = (int)((__builtin_bit_cast(unsigned, ax) >> 23) & 0xff) - 127;
    int qe = (e2 < -6 ? -6 : e2) - 3;
    float q = __builtin_bit_cast(float, (unsigned)((qe + 127) << 23));
    float r = rintf(ax / q) * q;
    if (r > 448.f) return (s << 7) | 0x7Eu;
    if (r < 0.001953125f) return s << 7;
    unsigned ub = __builtin_bit_cast(unsigned, r);
    int re = (int)((ub >> 23) & 0xff) - 127;
    if (re < -6) {
        unsigned m = (unsigned)rintf(r * 512.f);
        return (s << 7) | m;
    }
    return (s << 7) | ((unsigned)(re + 7) << 3) | ((ub >> 20) & 7u);
}
#endif

// pack 4 floats -> 4 fp8 bytes in one dword (byte i = value i)
static __device__ __forceinline__ unsigned int fp8x4_enc(float a, float b, float c, float d) {
#ifdef FP8_HW
    int p = __builtin_amdgcn_cvt_pk_fp8_f32(a, b, 0, false);
    p = __builtin_amdgcn_cvt_pk_fp8_f32(c, d, p, true);
    return (unsigned int)p;
#else
    return fp8_enc1(a) | (fp8_enc1(b) << 8) | (fp8_enc1(c) << 16) | (fp8_enc1(d) << 24);
#endif
}

// ---------------------------------------------------------------------------
// Per-block LDS bucket histogram (blocks < NBLK) + fused one-off setup work
// (blocks NBLK..NBLK+2): weight/bias prep, graph bounds, pooled zero + T' zero
// row + done-counter zero.
__global__ __launch_bounds__(256) void block_hist_setup(const int* __restrict__ dst,
                                                        int* __restrict__ hist,  // [nblk][NB]
                                                        int E, int NB, int NBLK,
                                                        const float* __restrict__ W1,
                                                        const float* __restrict__ W2,
                                                        const float* __restrict__ b1,
                                                        const float* __restrict__ b2,
                                                        unsigned short* __restrict__ wsw1,
                                                        unsigned short* __restrict__ wsw2,
                                                        float* __restrict__ pb1,
                                                        float* __restrict__ pb2,
                                                        const int* __restrict__ batch,
                                                        int* __restrict__ gstart,
                                                        float* __restrict__ pooled,
                                                        unsigned int* __restrict__ zrow,
                                                        int* __restrict__ donecnt,
                                                        int n, int G) {
    __shared__ int h[MAXNB];
    const int tid = threadIdx.x;
    if (blockIdx.x >= (unsigned)NBLK) {
        const int role = blockIdx.x - NBLK;
        if (role == 0) {
            for (int idx = tid; idx < 16384; idx += 256) {
                int nn = idx >> 7, k = idx & 127;
                wsw1[idx] = (unsigned short)(bfpack(W1[k * 128 + nn], 0.f) & 0xffffu);
                wsw2[idx] = (unsigned short)(bfpack(W2[CP(k) * 128 + nn], 0.f) & 0xffffu);
            }
            if (tid < 128) {
                pb1[tid] = b1[CP(tid)];
                pb2[tid] = b2[CP(tid)];
            }
        } else if (role == 1) {
            if (tid <= G) {
                int lo = 0, hi = n;
                while (lo < hi) { int mid = (lo + hi) >> 1; if (batch[mid] < tid) lo = mid + 1; else hi = mid; }
                gstart[tid] = lo;
            }
        } else {
            for (int i = tid; i < G * 128; i += 256) pooled[i] = 0.f;
            if (tid < 32) zrow[tid] = 0u;  // zero row at T' index N (sentinel target)
            if (tid == 0) donecnt[0] = 0;
        }
        return;
    }
    for (int i = tid; i < NB; i += 256) h[i] = 0;
    __syncthreads();
    const int base = blockIdx.x * CHUNK;
    int lim = base + CHUNK; if (lim > E) lim = E;
    for (int i = base + tid; i < lim; i += 256) atomicAdd(&h[dst[i] >> BSH], 1);
    __syncthreads();
    int* hrow = hist + (size_t)blockIdx.x * NB;
    for (int b = tid; b < NB; b += 256) hrow[b] = h[b];
}

// Exclusive scan over M = NB*NBLK counts in bucket-major order.
// bsum[blk] = raw block total (NOT scanned); consumers scan it locally.
__global__ void scanA(const int* __restrict__ hist, int* __restrict__ excl,
                      int* __restrict__ bsum, int M, int NB, int NBLK) {
    __shared__ int tmp[256];
    const int t = threadIdx.x;
    const int idx = blockIdx.x * 2048 + t * 8;
    int v[8], s = 0;
    #pragma unroll
    for (int i = 0; i < 8; ++i) {
        int p = idx + i;
        v[i] = (p < M) ? hist[(size_t)(p % NBLK) * NB + (p / NBLK)] : 0;
        s += v[i];
    }
    tmp[t] = s;
    __syncthreads();
    for (int off = 1; off < 256; off <<= 1) {
        int x = (t >= off) ? tmp[t - off] : 0;
        __syncthreads();
        tmp[t] += x;
        __syncthreads();
    }
    int run = tmp[t] - s;
    #pragma unroll
    for (int i = 0; i < 8; ++i) {
        int p = idx + i;
        if (p < M) excl[p] = run;
        run += v[i];
    }
    if (t == 255) bsum[blockIdx.x] = tmp[255];
}

// Local exclusive scan of raw bsum (<=256 entries) into bscan (LDS).
// Replaces the former 1-block scanB kernel (launch + stall saved); each
// consumer block recomputes it redundantly (~1 us of LDS ops).
static __device__ __forceinline__ void local_bscan(const int* __restrict__ bsum,
                                                   int nscan, int* bscan) {
    const int t = threadIdx.x;
    int s0 = (t < nscan) ? bsum[t] : 0;
    bscan[t] = s0;
    __syncthreads();
    for (int off = 1; off < 256; off <<= 1) {
        int x = (t >= off) ? bscan[t - off] : 0;
        __syncthreads();
        bscan[t] += x;
        __syncthreads();
    }
    int ex = bscan[t] - s0;
    __syncthreads();
    bscan[t] = ex;
    __syncthreads();
}

// Re-read edges; exact LDS cursors from scanned hist (+local bsum scan);
// write packed edge (src | node-in-bucket<<26) grouped by bucket.
__global__ __launch_bounds__(256) void bucket_scatter(const int* __restrict__ src,
                                                      const int* __restrict__ dst,
                                                      const int* __restrict__ excl,
                                                      const int* __restrict__ bsum,
                                                      unsigned int* __restrict__ packed,
                                                      int E, int NB, int NBLK, int nscan) {
    __shared__ int cur[MAXNB];
    __shared__ int bscan[256];
    const int tid = threadIdx.x;
    const int blk = blockIdx.x;
    local_bscan(bsum, nscan, bscan);
    for (int b = tid; b < NB; b += 256) {
        size_t p = (size_t)b * NBLK + blk;
        cur[b] = excl[p] + bscan[p >> 11];
    }
    __syncthreads();
    const int base = blk * CHUNK;
    int lim = base + CHUNK; if (lim > E) lim = E;
    for (int i = base + tid; i < lim; i += 256) {
        int d = dst[i];
        int s = src[i];
        int pos = atomicAdd(&cur[d >> BSH], 1);  // LDS atomic only
        packed[pos] = (unsigned)s | ((unsigned)(d & (BWD - 1)) << 26);
    }
}

// One block per bucket: in-bucket per-node counts -> PADDED CSR.
// Each node's edge run is padded to a multiple of 8 with sentinel entries
// (col = N -> zero row of T') so the gather runs ONLY full 8-wide legs.
// (Pad-16 measured WORSE in round 7: +46% sentinel row-loads cost more than
// the saved leg -> gather is line-service-bound, keep pad-8.)
__global__ __launch_bounds__(256) void bucket_to_csr(const unsigned int* __restrict__ packed,
                                                     const int* __restrict__ excl,
                                                     const int* __restrict__ bsum,
                                                     int* __restrict__ rowptr,
                                                     int* __restrict__ pdeg,
                                                     float* __restrict__ dinv,
                                                     int* __restrict__ col,
                                                     int E, int N, int NB, int NBLK, int nscan) {
    __shared__ int cnt[BWD];
    __shared__ int offs[BWD];
    __shared__ int ovf;
    __shared__ int bscan[256];
    const int b = blockIdx.x;
    const int tid = threadIdx.x;
    local_bscan(bsum, nscan, bscan);
    size_t p0 = (size_t)b * NBLK;
    const int base = excl[p0] + bscan[p0 >> 11];
    int next;
    if (b + 1 < NB) {
        size_t p1 = (size_t)(b + 1) * NBLK;
        next = excl[p1] + bscan[p1 >> 11];
    } else {
        next = E;
    }
    if (tid < BWD) cnt[tid] = 0;
    if (tid == 0) ovf = 0;
    __syncthreads();
    for (int i = base + tid; i < next; i += 256) atomicAdd(&cnt[packed[i] >> 26], 1);
    __syncthreads();
    const int rc = (tid < BWD) ? cnt[tid] : 0;   // real count
    if (tid == 0) {
        int run = 0;
        for (int j = 0; j < BWD; ++j) { offs[j] = run; run += (cnt[j] + 7) & ~7; }
        if (run > CSRCAP) {  // astronomically unlikely; drop padding
            ovf = 1;
            run = 0;
            for (int j = 0; j < BWD; ++j) { offs[j] = run; run += cnt[j]; }
        }
    }
    __syncthreads();
    const int cbase = b * CSRCAP;
    if (tid < BWD) {
        int node = (b << BSH) + tid;
        if (node < N) {
            int pd = ovf ? rc : ((rc + 7) & ~7);
            int st = cbase + offs[tid];
            rowptr[node] = st;
            pdeg[node] = pd;
            dinv[node] = rsqrtf((float)rc + 1.0f);
            for (int k = rc; k < pd; ++k) col[st + k] = N;  // sentinel -> zero row
        }
        cnt[tid] = offs[tid];  // reuse as in-bucket cursors
    }
    __syncthreads();
    for (int i = base + tid; i < next; i += 256) {
        unsigned int u = packed[i];
        int j = u >> 26;
        int pos = cbase + atomicAdd(&cnt[j], 1);  // LDS atomic only
        col[pos] = (int)(u & 0x03ffffffu);
    }
}

// ---------------------------------------------------------------------------
// MFMA GEMM with LDS-staged W (round-8 proven: 328->277 us total).
// wsw is 32 KB = exactly L1 -> streaming A-rows evict it; staging into LDS
// (XOR swizzle, conflict-free) turns the 8 serial W-legs into LDS reads.
// A-loads issue BEFORE staging so the HBM A-leg hides under staging+barrier.
// Never writes row N (the sentinel zero row survives both layers).
template <bool BF16IN>
__global__ __launch_bounds__(256, 4) void gemm_mfma(const void* __restrict__ Xv,
                                                    const unsigned short* __restrict__ wsw,
                                                    const float* __restrict__ rowscale,
                                                    uint2* __restrict__ Out, int n) {
    __shared__ char sW[32768];
    const int tid = threadIdx.x;
    const int w = tid >> 6;
    const int lane = tid & 63;
    const int q = lane >> 4;
    const int m15 = lane & 15;
    const int rbase = blockIdx.x * 64;

    const int arow = rbase + w * 16 + m15;
    const int srow = (arow < n) ? arow : (n - 1);  // clamped; garbage rows never stored

    // ---- issue A loads first (HBM leg overlaps W staging + barrier) ----
    uint4 ta[4];
    float4 tf[8];
    if (BF16IN) {
        const unsigned short* xr = (const unsigned short*)Xv + (size_t)srow * 128 + q * 8;
        #pragma unroll
        for (int kk = 0; kk < 4; ++kk) ta[kk] = *(const uint4*)(xr + kk * 32);
    } else {
        const float* xr = (const float*)Xv + (size_t)srow * 128 + q * 8;
        #pragma unroll
        for (int kk = 0; kk < 4; ++kk) {
            tf[2 * kk]     = *(const float4*)(xr + kk * 32);
            tf[2 * kk + 1] = *(const float4*)(xr + kk * 32 + 4);
        }
    }

    // ---- stage W into LDS (2048 x 16B, XOR swizzle) ----
    #pragma unroll
    for (int it = 0; it < 8; ++it) {
        int fi = it * 256 + tid;
        uint4 v = ((const uint4*)wsw)[fi];
        *(uint4*)(sW + ((fi * 16) ^ (((fi >> 4) & 7) << 4))) = v;
    }
    __syncthreads();

    // ---- pack A fragments ----
    v8s a[4];
    if (BF16IN) {
        #pragma unroll
        for (int kk = 0; kk < 4; ++kk) a[kk] = __builtin_bit_cast(v8s, ta[kk]);
    } else {
        #pragma unroll
        for (int kk = 0; kk < 4; ++kk) {
            uint4 p;
            p.x = bfpack(tf[2 * kk].x, tf[2 * kk].y);
            p.y = bfpack(tf[2 * kk].z, tf[2 * kk].w);
            p.z = bfpack(tf[2 * kk + 1].x, tf[2 * kk + 1].y);
            p.w = bfpack(tf[2 * kk + 1].z, tf[2 * kk + 1].w);
            a[kk] = __builtin_bit_cast(v8s, p);
        }
    }

    // ---- inner loop: W fragments from LDS (register double-buffer) ----
    const int swz = (m15 & 7) << 4;
    v8s bcur[4], bnxt[4];
    #pragma unroll
    for (int kk = 0; kk < 4; ++kk)
        bcur[kk] = *(const v8s*)(sW + (((m15 * 16 + kk * 4 + q) * 16) ^ swz));

    v4f acc[8];
    #pragma unroll
    for (int nt = 0; nt < 8; ++nt) acc[nt] = (v4f){0.f, 0.f, 0.f, 0.f};

    #pragma unroll
    for (int nt = 0; nt < 8; ++nt) {
        if (nt < 7) {
            #pragma unroll
            for (int kk = 0; kk < 4; ++kk)
                bnxt[kk] = *(const v8s*)(sW +
                    (((((nt + 1) * 16 + m15) * 16 + kk * 4 + q) * 16) ^ swz));
        }
        #pragma unroll
        for (int kk = 0; kk < 4; ++kk)
            acc[nt] = __builtin_amdgcn_mfma_f32_16x16x32_bf16(a[kk], bcur[kk], acc[nt], 0, 0, 0);
        #pragma unroll
        for (int kk = 0; kk < 4; ++kk) bcur[kk] = bnxt[kk];
    }

    // epilogue: D row = q*4+reg, col = nt*16+m15 -> P-order bytes p=m15*8+nt
    #pragma unroll
    for (int reg = 0; reg < 4; ++reg) {
        int row = rbase + w * 16 + q * 4 + reg;
        if (row < n) {
            float sc = rowscale[row];
            unsigned int d0 = fp8x4_enc(acc[0][reg] * sc, acc[1][reg] * sc,
                                        acc[2][reg] * sc, acc[3][reg] * sc);
            unsigned int d1 = fp8x4_enc(acc[4][reg] * sc, acc[5][reg] * sc,
                                        acc[6][reg] * sc, acc[7][reg] * sc);
            Out[(size_t)row * 16 + m15] = make_uint2(d0, d1);
        }
    }
}

// ---------------------------------------------------------------------------
// Fused CSR gather + epilogue on pre-scaled fp8 T' (P-ordered rows):
//   h[d] = relu( (sum_{s in in(d)} T'[s] + T'[d]) * dinv[d] + pbias )
// HALF-wave per dst node (32 lanes x 1 dword = 128 B row) — the round-0
// proven shape (VGPR 28, loads batch-hoisted). CSR is padded to multiples
// of 8 with zero-row sentinels -> per node exactly pdeg/8 (1-3) 8-wide legs.
__global__ __launch_bounds__(256) void gather_fused(const unsigned int* __restrict__ T32,
                                                    const int* __restrict__ rowptr,
                                                    const int* __restrict__ pdeg,
                                                    const int* __restrict__ col,
                                                    const float* __restrict__ dinv,
                                                    const float* __restrict__ pbias,
                                                    uint2* __restrict__ H, int n) {
    const int wave = (blockIdx.x * 256 + threadIdx.x) >> 6;
    const int d = wave * 2 + ((threadIdx.x >> 5) & 1);
    const int hl = threadIdx.x & 31;
    if (d >= n) return;
    int e = rowptr[d];
    const int end = e + pdeg[d];

    v2f sl0 = {0.f, 0.f}, sh0 = {0.f, 0.f}, sl1 = {0.f, 0.f}, sh1 = {0.f, 0.f};

    if ((e & 1) && e < end) {  // never runs on padded CSR (kept for fallback)
        unsigned int u = T32[(size_t)col[e] * 32 + hl];
        sl0 += fp8_dec_lo(u); sh0 += fp8_dec_hi(u);
        ++e;
    }
    for (; e + 7 < end; e += 8) {
        int2 p01 = *(const int2*)(col + e);
        int2 p23 = *(const int2*)(col + e + 2);
        int2 p45 = *(const int2*)(col + e + 4);
        int2 p67 = *(const int2*)(col + e + 6);
        unsigned int u0 = T32[(size_t)p01.x * 32 + hl];
        unsigned int u1 = T32[(size_t)p01.y * 32 + hl];
        unsigned int u2 = T32[(size_t)p23.x * 32 + hl];
        unsigned int u3 = T32[(size_t)p23.y * 32 + hl];
        unsigned int u4 = T32[(size_t)p45.x * 32 + hl];
        unsigned int u5 = T32[(size_t)p45.y * 32 + hl];
        unsigned int u6 = T32[(size_t)p67.x * 32 + hl];
        unsigned int u7 = T32[(size_t)p67.y * 32 + hl];
        sl0 += fp8_dec_lo(u0); sh0 += fp8_dec_hi(u0);
        sl1 += fp8_dec_lo(u1); sh1 += fp8_dec_hi(u1);
        sl0 += fp8_dec_lo(u2); sh0 += fp8_dec_hi(u2);
        sl1 += fp8_dec_lo(u3); sh1 += fp8_dec_hi(u3);
        sl0 += fp8_dec_lo(u4); sh0 += fp8_dec_hi(u4);
        sl1 += fp8_dec_lo(u5); sh1 += fp8_dec_hi(u5);
        sl0 += fp8_dec_lo(u6); sh0 += fp8_dec_hi(u6);
        sl1 += fp8_dec_lo(u7); sh1 += fp8_dec_hi(u7);
    }
    for (; e + 1 < end; e += 2) {  // never runs on padded CSR
        int2 p = *(const int2*)(col + e);
        unsigned int u0 = T32[(size_t)p.x * 32 + hl];
        unsigned int u1 = T32[(size_t)p.y * 32 + hl];
        sl0 += fp8_dec_lo(u0); sh0 += fp8_dec_hi(u0);
        sl1 += fp8_dec_lo(u1); sh1 += fp8_dec_hi(u1);
    }
    if (e < end) {                 // never runs on padded CSR
        unsigned int u = T32[(size_t)col[e] * 32 + hl];
        sl0 += fp8_dec_lo(u); sh0 += fp8_dec_hi(u);
    }

    // self term
    unsigned int su = T32[(size_t)d * 32 + hl];
    sl0 += fp8_dec_lo(su); sh0 += fp8_dec_hi(su);
    v2f sl = sl0 + sl1, sh = sh0 + sh1;

    const float di = dinv[d];
    const float4 bv = ((const float4*)pbias)[hl];
    float o0 = fmaxf(fmaf(sl.x, di, bv.x), 0.f);
    float o1 = fmaxf(fmaf(sl.y, di, bv.y), 0.f);
    float o2 = fmaxf(fmaf(sh.x, di, bv.z), 0.f);
    float o3 = fmaxf(fmaf(sh.y, di, bv.w), 0.f);
    uint2 o;
    o.x = bfpack(o0, o1);
    o.y = bfpack(o2, o3);
    H[(size_t)d * 32 + hl] = o;
}

// ---------------------------------------------------------------------------
// Layer-2 gather with fused mean-pool at 64-node granularity (round-9 proven)
// + FUSED HEADS: the last block to finish (device-scope done-counter) computes
// action_mean/std/value directly, removing the head_kernel launch. pooled is
// written only via device-scope atomics (coherent point), so the last block
// reads it with agent-scope atomic loads (bypass stale XCD caches).
__global__ __launch_bounds__(256) void gather_pool(const unsigned int* __restrict__ T32,
                                                   const int* __restrict__ rowptr,
                                                   const int* __restrict__ pdeg,
                                                   const int* __restrict__ col,
                                                   const float* __restrict__ dinv,
                                                   const float* __restrict__ pbias,
                                                   float* __restrict__ pooled,
                                                   const int* __restrict__ batch,
                                                   int* __restrict__ donecnt,
                                                   const int* __restrict__ gstart,
                                                   const float* __restrict__ Wa,
                                                   const float* __restrict__ ba,
                                                   const float* __restrict__ Wv,
                                                   const float* __restrict__ bv2,
                                                   const float* __restrict__ log_std,
                                                   float* __restrict__ out,
                                                   int n, int G) {
    __shared__ float pacc[256];   // [2 graph slots][128 dims]
    const int tid = threadIdx.x;
    const int hw = tid >> 5;      // half-wave 0..7
    const int hl = tid & 31;
    const int base = blockIdx.x * 64;
    pacc[tid] = 0.f;
    const int g0 = batch[base < n ? base : (n - 1)];
    __syncthreads();

    const float4 bv = ((const float4*)pbias)[hl];
    float r0a = 0.f, r0b = 0.f, r0c = 0.f, r0d = 0.f;   // graph slot 0
    float r1a = 0.f, r1b = 0.f, r1c = 0.f, r1d = 0.f;   // graph slot 1

    for (int it = 0; it < 8; ++it) {
        const int d = base + hw * 8 + it;   // 8 consecutive nodes per half-wave
        if (d < n) {
            int e = rowptr[d];
            const int end = e + pdeg[d];

            v2f sl0 = {0.f, 0.f}, sh0 = {0.f, 0.f}, sl1 = {0.f, 0.f}, sh1 = {0.f, 0.f};

            if ((e & 1) && e < end) {  // never runs on padded CSR (fallback only)
                unsigned int u = T32[(size_t)col[e] * 32 + hl];
                sl0 += fp8_dec_lo(u); sh0 += fp8_dec_hi(u);
                ++e;
            }
            for (; e + 7 < end; e += 8) {
                int2 p01 = *(const int2*)(col + e);
                int2 p23 = *(const int2*)(col + e + 2);
                int2 p45 = *(const int2*)(col + e + 4);
                int2 p67 = *(const int2*)(col + e + 6);
                unsigned int u0 = T32[(size_t)p01.x * 32 + hl];
                unsigned int u1 = T32[(size_t)p01.y * 32 + hl];
                unsigned int u2 = T32[(size_t)p23.x * 32 + hl];
                unsigned int u3 = T32[(size_t)p23.y * 32 + hl];
                unsigned int u4 = T32[(size_t)p45.x * 32 + hl];
                unsigned int u5 = T32[(size_t)p45.y * 32 + hl];
                unsigned int u6 = T32[(size_t)p67.x * 32 + hl];
                unsigned int u7 = T32[(size_t)p67.y * 32 + hl];
                sl0 += fp8_dec_lo(u0); sh0 += fp8_dec_hi(u0);
                sl1 += fp8_dec_lo(u1); sh1 += fp8_dec_hi(u1);
                sl0 += fp8_dec_lo(u2); sh0 += fp8_dec_hi(u2);
                sl1 += fp8_dec_lo(u3); sh1 += fp8_dec_hi(u3);
                sl0 += fp8_dec_lo(u4); sh0 += fp8_dec_hi(u4);
                sl1 += fp8_dec_lo(u5); sh1 += fp8_dec_hi(u5);
                sl0 += fp8_dec_lo(u6); sh0 += fp8_dec_hi(u6);
                sl1 += fp8_dec_lo(u7); sh1 += fp8_dec_hi(u7);
            }
            for (; e + 1 < end; e += 2) {  // fallback only
                int2 p = *(const int2*)(col + e);
                unsigned int u0 = T32[(size_t)p.x * 32 + hl];
                unsigned int u1 = T32[(size_t)p.y * 32 + hl];
                sl0 += fp8_dec_lo(u0); sh0 += fp8_dec_hi(u0);
                sl1 += fp8_dec_lo(u1); sh1 += fp8_dec_hi(u1);
            }
            if (e < end) {                 // fallback only
                unsigned int u = T32[(size_t)col[e] * 32 + hl];
                sl0 += fp8_dec_lo(u); sh0 += fp8_dec_hi(u);
            }

            unsigned int su = T32[(size_t)d * 32 + hl];  // self term
            sl0 += fp8_dec_lo(su); sh0 += fp8_dec_hi(su);
            v2f sl = sl0 + sl1, sh = sh0 + sh1;

            const float di = dinv[d];
            float o0 = fmaxf(fmaf(sl.x, di, bv.x), 0.f);
            float o1 = fmaxf(fmaf(sl.y, di, bv.y), 0.f);
            float o2 = fmaxf(fmaf(sh.x, di, bv.z), 0.f);
            float o3 = fmaxf(fmaf(sh.y, di, bv.w), 0.f);

            const int gi = batch[d] - g0;
            if (gi == 0) {
                r0a += o0; r0b += o1; r0c += o2; r0d += o3;
            } else if (gi == 1) {
                r1a += o0; r1b += o1; r1c += o2; r1d += o3;
            } else {  // >2 graphs in a 64-node window: ~impossible, stay correct
                atomicAdd(&pooled[(size_t)(g0 + gi) * 128 + 4 * hl + 0], o0);
                atomicAdd(&pooled[(size_t)(g0 + gi) * 128 + 4 * hl + 1], o1);
                atomicAdd(&pooled[(size_t)(g0 + gi) * 128 + 4 * hl + 2], o2);
                atomicAdd(&pooled[(size_t)(g0 + gi) * 128 + 4 * hl + 3], o3);
            }
        }
    }

    // reduce the 8 half-waves' register partials in LDS
    atomicAdd(&pacc[4 * hl + 0], r0a);
    atomicAdd(&pacc[4 * hl + 1], r0b);
    atomicAdd(&pacc[4 * hl + 2], r0c);
    atomicAdd(&pacc[4 * hl + 3], r0d);
    if (r1a != 0.f || r1b != 0.f || r1c != 0.f || r1d != 0.f) {
        atomicAdd(&pacc[128 + 4 * hl + 0], r1a);
        atomicAdd(&pacc[128 + 4 * hl + 1], r1b);
        atomicAdd(&pacc[128 + 4 * hl + 2], r1c);
        atomicAdd(&pacc[128 + 4 * hl + 3], r1d);
    }
    __syncthreads();
    float v = pacc[tid];
    if (v != 0.f) {               // slot-1 mostly all-zero; also guards g0+1>=G
        int gg = g0 + (tid >> 7);
        atomicAdd(&pooled[(size_t)gg * 128 + (tid & 127)], v);
    }

    // ---- last-block-done head computation (replaces head_kernel launch) ----
    __threadfence();              // make this block's pooled atomics visible
    __syncthreads();              // all threads' flushes + fences done
    __shared__ int lastv;
    if (tid == 0) lastv = (atomicAdd(donecnt, 1) == (int)gridDim.x - 1);
    __syncthreads();
    if (!lastv) return;
    __threadfence();              // acquire side

    __shared__ float sp8[8][128];
    const int grp = tid >> 5;     // 8 lane-groups of 32
    const int l32 = tid & 31;
    for (int g = grp; g < G; g += 8) {
        float inv = 1.0f / fmaxf((float)(gstart[g + 1] - gstart[g]), 1.0f);
        for (int k = l32; k < 128; k += 32)
            sp8[grp][k] = __hip_atomic_load(&pooled[(size_t)g * 128 + k],
                                            __ATOMIC_RELAXED, __HIP_MEMORY_SCOPE_AGENT) * inv;
        // same-wave LDS write->read: lockstep, compiler inserts lgkmcnt
        float sa = 0.f;
        #pragma unroll 8
        for (int k = 0; k < 128; ++k) sa = fmaf(sp8[grp][k], Wa[CP(k) * ADIM + l32], sa);
        out[g * ADIM + l32] = sa + ba[l32];
        float pv = 0.f;
        for (int k = l32; k < 128; k += 32) pv = fmaf(sp8[grp][k], Wv[CP(k)], pv);
        #pragma unroll
        for (int o = 16; o; o >>= 1) pv += __shfl_down(pv, o, 32);
        if (l32 == 0) out[G * ADIM + ADIM + g] = pv + bv2[0];
    }
    if (tid < ADIM) out[G * ADIM + tid] = expf(log_std[tid]);
}

// ---------------------------------------------------------------------------
extern "C" void kernel_launch(void* const* d_in, const int* in_sizes, int n_in,
                              void* d_out, int out_size, void* d_ws, size_t ws_size,
                              hipStream_t stream) {
    const float* x       = (const float*)d_in[0];
    const int*   ei      = (const int*)d_in[1];
    const int*   batch   = (const int*)d_in[2];
    const float* W1      = (const float*)d_in[3];
    const float* b1      = (const float*)d_in[4];
    const float* W2      = (const float*)d_in[5];
    const float* b2      = (const float*)d_in[6];
    const float* Wa      = (const float*)d_in[7];
    const float* ba      = (const float*)d_in[8];
    const float* Wv      = (const float*)d_in[9];
    const float* bv      = (const float*)d_in[10];
    const float* log_std = (const float*)d_in[11];
    float* out = (float*)d_out;

    const int N = in_sizes[0] / FDIM;
    const int E = in_sizes[1] / 2;
    const int G = (out_size - ADIM) / (ADIM + 1);
    const int NB = (N + BWD - 1) >> BSH;          // buckets (<= MAXNB for N <= 131072)
    const int NBLK = (E + CHUNK - 1) / CHUNK;     // binning blocks
    const int M = NB * NBLK;                      // scan length
    const int nscanA = (M + 2047) / 2048;         // <= 256

    const int* src = ei;
    const int* dst = ei + E;

    auto align = [](size_t v) { return (v + 255) & ~(size_t)255; };
    char* ws = (char*)d_ws;
    size_t off = 0;
    int*   hist   = (int*)(ws + off);   off = align(off + (size_t)M * 4);
    int*   excl   = (int*)(ws + off);   off = align(off + (size_t)M * 4);
    int*   bsum   = (int*)(ws + off);   off = align(off + (size_t)256 * 4);
    int*   rowptr = (int*)(ws + off);   off = align(off + (size_t)(N + 1) * 4);
    int*   pdeg   = (int*)(ws + off);   off = align(off + (size_t)N * 4);
    int*   gstart = (int*)(ws + off);   off = align(off + (size_t)(G + 1) * 4);
    float* dinv   = (float*)(ws + off); off = align(off + (size_t)N * 4);
    float* pooled = (float*)(ws + off); off = align(off + (size_t)G * HDIM * 4);
    int*   donecnt = (int*)(ws + off);  off = align(off + (size_t)16 * 4);
    unsigned short* wsw1 = (unsigned short*)(ws + off); off = align(off + (size_t)16384 * 2);
    unsigned short* wsw2 = (unsigned short*)(ws + off); off = align(off + (size_t)16384 * 2);
    float* pb1    = (float*)(ws + off); off = align(off + (size_t)128 * 4);
    float* pb2    = (float*)(ws + off); off = align(off + (size_t)128 * 4);
    unsigned int* packed = (unsigned int*)(ws + off); off = align(off + (size_t)E * 4);
    int*   col    = (int*)(ws + off);   off = align(off + (size_t)NB * CSRCAP * 4);  // padded CSR
    unsigned int* bufA = (unsigned int*)(ws + off); off = align(off + (size_t)(N + 1) * 32 * 4);  // fp8 (N+1)x128; row N = zeros
    unsigned int* bufB = (unsigned int*)(ws + off); off = align(off + (size_t)N * 64 * 4);  // bf16 N x 128 (P-order)
    (void)ws_size;

    unsigned int* zrow = bufA + (size_t)N * 32;

    const int blkGemm = (N + 63) / 64;
    const int blkGather = (N + 7) / 8;            // half-wave per node, 8 nodes/block
    const int blkGP = (N + 63) / 64;              // 64 nodes per gather_pool block

    // ---- binning -> padded CSR + dinv (no global atomics); setup fused in ----
    block_hist_setup<<<NBLK + 3, 256, 0, stream>>>(dst, hist, E, NB, NBLK,
                                                   W1, W2, b1, b2, wsw1, wsw2, pb1, pb2,
                                                   batch, gstart, pooled, zrow, donecnt, N, G);
    scanA<<<nscanA, 256, 0, stream>>>(hist, excl, bsum, M, NB, NBLK);
    bucket_scatter<<<NBLK, 256, 0, stream>>>(src, dst, excl, bsum, packed, E, NB, NBLK, nscanA);
    bucket_to_csr<<<NB, 256, 0, stream>>>(packed, excl, bsum, rowptr, pdeg, dinv, col,
                                          E, N, NB, NBLK, nscanA);

    // ---- layer 1 (fp32 in, fp8 P-order out) ----
    gemm_mfma<false><<<blkGemm, 256, 0, stream>>>(x, wsw1, dinv, (uint2*)bufA, N);
    gather_fused<<<blkGather, 256, 0, stream>>>(bufA, rowptr, pdeg, col, dinv, pb1,
                                                (uint2*)bufB, N);

    // ---- layer 2 (bf16 P-order in, fp8 P-order out) + fused mean-pool+heads ----
    gemm_mfma<true><<<blkGemm, 256, 0, stream>>>(bufB, wsw2, dinv, (uint2*)bufA, N);
    gather_pool<<<blkGP, 256, 0, stream>>>(bufA, rowptr, pdeg, col, dinv, pb2,
                                           pooled, batch, donecnt,
                                           gstart, Wa, ba, Wv, bv, log_std, out, N, G);
}

// Round 11
// 262.699 us; speedup vs baseline: 1.5975x; 1.5975x over previous
//
#include <hip/hip_runtime.h>
#include <hip/hip_bf16.h>

#define FDIM 128
#define HDIM 128
#define ADIM 32
#define BSH 6        // bucket shift: 64 dst nodes per bucket
#define BWD 64
#define CHUNK 8192   // edges per binning block
#define MAXNB 2048   // max buckets supported (N <= 131072)
#define CSRCAP 2048  // padded col capacity per bucket (mean ~1248 @pad8, >16 sigma)

// Storage permutation for T'/H rows: byte position p holds col c(p).
// p = m15*8 + nt  <->  col = nt*16 + m15 ;  c(p) = ((p&7)<<4) | (p>>3)
#define CP(p) ((((p) & 7) << 4) | ((p) >> 3))

typedef short v8s __attribute__((ext_vector_type(8)));
typedef float v4f __attribute__((ext_vector_type(4)));
typedef float v2f __attribute__((ext_vector_type(2)));

// bf16x2 helpers (bitwise; bf16->fp32 exact, fp32->bf16 RNE)
static __device__ __forceinline__ float bflo(unsigned int u) {
    return __builtin_bit_cast(float, u << 16);
}
static __device__ __forceinline__ float bfhi(unsigned int u) {
    return __builtin_bit_cast(float, u & 0xffff0000u);
}
static __device__ __forceinline__ unsigned int bfpack(float a, float b) {
    unsigned int ua = __builtin_bit_cast(unsigned int, a);
    unsigned int ub = __builtin_bit_cast(unsigned int, b);
    ua += 0x7fffu + ((ua >> 16) & 1u);
    ub += 0x7fffu + ((ub >> 16) & 1u);
    return (ua >> 16) | (ub & 0xffff0000u);
}

// ---------------------------------------------------------------------------
// fp8 e4m3 (OCP) helpers. HW path: gfx950 cvt instructions.
#if defined(__has_builtin) && __has_builtin(__builtin_amdgcn_cvt_pk_f32_fp8) && \
    __has_builtin(__builtin_amdgcn_cvt_pk_fp8_f32)
#define FP8_HW 1
#endif

static __device__ __forceinline__ v2f fp8_dec_lo(unsigned int u) {
#ifdef FP8_HW
    return __builtin_amdgcn_cvt_pk_f32_fp8(u, false);
#else
    v2f r;
    #pragma unroll
    for (int i = 0; i < 2; ++i) {
        unsigned b = (u >> (8 * i)) & 0xffu;
        unsigned s = b >> 7, e = (b >> 3) & 0xfu, m = b & 7u;
        float v = (e == 0) ? (float)m * 0.001953125f
                           : __builtin_bit_cast(float, ((e + 120u) << 23) | (m << 20));
        r[i] = s ? -v : v;
    }
    return r;
#endif
}
static __device__ __forceinline__ v2f fp8_dec_hi(unsigned int u) {
#ifdef FP8_HW
    return __builtin_amdgcn_cvt_pk_f32_fp8(u, true);
#else
    return fp8_dec_lo(u >> 16);
#endif
}

#ifndef FP8_HW
static __device__ __forceinline__ unsigned int fp8_enc1(float x) {
    unsigned s = __builtin_bit_cast(unsigned, x) >> 31;
    float ax = fabsf(x);
    if (ax > 448.f) return (s << 7) | 0x7Eu;
    if (ax < 0.0009765625f) return s << 7;
    int e2 = (int)((__builtin_bit_cast(unsigned, ax) >> 23) & 0xff) - 127;
    int qe = (e2 < -6 ? -6 : e2) - 3;
    float q = __builtin_bit_cast(float, (unsigned)((qe + 127) << 23));
    float r = rintf(ax / q) * q;
    if (r > 448.f) return (s << 7) | 0x7Eu;
    if (r < 0.001953125f) return s << 7;
    unsigned ub = __builtin_bit_cast(unsigned, r);
    int re = (int)((ub >> 23) & 0xff) - 127;
    if (re < -6) {
        unsigned m = (unsigned)rintf(r * 512.f);
        return (s << 7) | m;
    }
    return (s << 7) | ((unsigned)(re + 7) << 3) | ((ub >> 20) & 7u);
}
#endif

// pack 4 floats -> 4 fp8 bytes in one dword (byte i = value i)
static __device__ __forceinline__ unsigned int fp8x4_enc(float a, float b, float c, float d) {
#ifdef FP8_HW
    int p = __builtin_amdgcn_cvt_pk_fp8_f32(a, b, 0, false);
    p = __builtin_amdgcn_cvt_pk_fp8_f32(c, d, p, true);
    return (unsigned int)p;
#else
    return fp8_enc1(a) | (fp8_enc1(b) << 8) | (fp8_enc1(c) << 16) | (fp8_enc1(d) << 24);
#endif
}

// ---------------------------------------------------------------------------
// Per-block LDS bucket histogram (blocks < NBLK) + fused one-off setup work
// (blocks NBLK..NBLK+2): weight/bias prep, graph bounds, pooled zero + T' zero row.
__global__ __launch_bounds__(256) void block_hist_setup(const int* __restrict__ dst,
                                                        int* __restrict__ hist,  // [nblk][NB]
                                                        int E, int NB, int NBLK,
                                                        const float* __restrict__ W1,
                                                        const float* __restrict__ W2,
                                                        const float* __restrict__ b1,
                                                        const float* __restrict__ b2,
                                                        unsigned short* __restrict__ wsw1,
                                                        unsigned short* __restrict__ wsw2,
                                                        float* __restrict__ pb1,
                                                        float* __restrict__ pb2,
                                                        const int* __restrict__ batch,
                                                        int* __restrict__ gstart,
                                                        float* __restrict__ pooled,
                                                        unsigned int* __restrict__ zrow,
                                                        int n, int G) {
    __shared__ int h[MAXNB];
    const int tid = threadIdx.x;
    if (blockIdx.x >= (unsigned)NBLK) {
        const int role = blockIdx.x - NBLK;
        if (role == 0) {
            for (int idx = tid; idx < 16384; idx += 256) {
                int nn = idx >> 7, k = idx & 127;
                wsw1[idx] = (unsigned short)(bfpack(W1[k * 128 + nn], 0.f) & 0xffffu);
                wsw2[idx] = (unsigned short)(bfpack(W2[CP(k) * 128 + nn], 0.f) & 0xffffu);
            }
            if (tid < 128) {
                pb1[tid] = b1[CP(tid)];
                pb2[tid] = b2[CP(tid)];
            }
        } else if (role == 1) {
            if (tid <= G) {
                int lo = 0, hi = n;
                while (lo < hi) { int mid = (lo + hi) >> 1; if (batch[mid] < tid) lo = mid + 1; else hi = mid; }
                gstart[tid] = lo;
            }
        } else {
            for (int i = tid; i < G * 128; i += 256) pooled[i] = 0.f;
            if (tid < 32) zrow[tid] = 0u;  // zero row at T' index N (sentinel target)
        }
        return;
    }
    for (int i = tid; i < NB; i += 256) h[i] = 0;
    __syncthreads();
    const int base = blockIdx.x * CHUNK;
    int lim = base + CHUNK; if (lim > E) lim = E;
    for (int i = base + tid; i < lim; i += 256) atomicAdd(&h[dst[i] >> BSH], 1);
    __syncthreads();
    int* hrow = hist + (size_t)blockIdx.x * NB;
    for (int b = tid; b < NB; b += 256) hrow[b] = h[b];
}

// Exclusive scan over M = NB*NBLK counts in bucket-major order.
// bsum[blk] = raw block total (NOT scanned); consumers scan it locally.
__global__ void scanA(const int* __restrict__ hist, int* __restrict__ excl,
                      int* __restrict__ bsum, int M, int NB, int NBLK) {
    __shared__ int tmp[256];
    const int t = threadIdx.x;
    const int idx = blockIdx.x * 2048 + t * 8;
    int v[8], s = 0;
    #pragma unroll
    for (int i = 0; i < 8; ++i) {
        int p = idx + i;
        v[i] = (p < M) ? hist[(size_t)(p % NBLK) * NB + (p / NBLK)] : 0;
        s += v[i];
    }
    tmp[t] = s;
    __syncthreads();
    for (int off = 1; off < 256; off <<= 1) {
        int x = (t >= off) ? tmp[t - off] : 0;
        __syncthreads();
        tmp[t] += x;
        __syncthreads();
    }
    int run = tmp[t] - s;
    #pragma unroll
    for (int i = 0; i < 8; ++i) {
        int p = idx + i;
        if (p < M) excl[p] = run;
        run += v[i];
    }
    if (t == 255) bsum[blockIdx.x] = tmp[255];
}

// Local exclusive scan of raw bsum (<=256 entries) into bscan (LDS).
// Replaces the former 1-block scanB kernel (launch + stall saved); each
// consumer block recomputes it redundantly (~1 us of LDS ops). Fence-free.
static __device__ __forceinline__ void local_bscan(const int* __restrict__ bsum,
                                                   int nscan, int* bscan) {
    const int t = threadIdx.x;
    int s0 = (t < nscan) ? bsum[t] : 0;
    bscan[t] = s0;
    __syncthreads();
    for (int off = 1; off < 256; off <<= 1) {
        int x = (t >= off) ? bscan[t - off] : 0;
        __syncthreads();
        bscan[t] += x;
        __syncthreads();
    }
    int ex = bscan[t] - s0;
    __syncthreads();
    bscan[t] = ex;
    __syncthreads();
}

// Re-read edges; exact LDS cursors from scanned hist (+local bsum scan);
// write packed edge (src | node-in-bucket<<26) grouped by bucket.
__global__ __launch_bounds__(256) void bucket_scatter(const int* __restrict__ src,
                                                      const int* __restrict__ dst,
                                                      const int* __restrict__ excl,
                                                      const int* __restrict__ bsum,
                                                      unsigned int* __restrict__ packed,
                                                      int E, int NB, int NBLK, int nscan) {
    __shared__ int cur[MAXNB];
    __shared__ int bscan[256];
    const int tid = threadIdx.x;
    const int blk = blockIdx.x;
    local_bscan(bsum, nscan, bscan);
    for (int b = tid; b < NB; b += 256) {
        size_t p = (size_t)b * NBLK + blk;
        cur[b] = excl[p] + bscan[p >> 11];
    }
    __syncthreads();
    const int base = blk * CHUNK;
    int lim = base + CHUNK; if (lim > E) lim = E;
    for (int i = base + tid; i < lim; i += 256) {
        int d = dst[i];
        int s = src[i];
        int pos = atomicAdd(&cur[d >> BSH], 1);  // LDS atomic only
        packed[pos] = (unsigned)s | ((unsigned)(d & (BWD - 1)) << 26);
    }
}

// One block per bucket: in-bucket per-node counts -> PADDED CSR.
// Each node's edge run is padded to a multiple of 8 with sentinel entries
// (col = N -> zero row of T') so the gather runs ONLY full 8-wide legs.
// (Pad-16 measured WORSE in round 7: +46% sentinel row-loads cost more than
// the saved leg -> gather is line-service-bound, keep pad-8.)
__global__ __launch_bounds__(256) void bucket_to_csr(const unsigned int* __restrict__ packed,
                                                     const int* __restrict__ excl,
                                                     const int* __restrict__ bsum,
                                                     int* __restrict__ rowptr,
                                                     int* __restrict__ pdeg,
                                                     float* __restrict__ dinv,
                                                     int* __restrict__ col,
                                                     int E, int N, int NB, int NBLK, int nscan) {
    __shared__ int cnt[BWD];
    __shared__ int offs[BWD];
    __shared__ int ovf;
    __shared__ int bscan[256];
    const int b = blockIdx.x;
    const int tid = threadIdx.x;
    local_bscan(bsum, nscan, bscan);
    size_t p0 = (size_t)b * NBLK;
    const int base = excl[p0] + bscan[p0 >> 11];
    int next;
    if (b + 1 < NB) {
        size_t p1 = (size_t)(b + 1) * NBLK;
        next = excl[p1] + bscan[p1 >> 11];
    } else {
        next = E;
    }
    if (tid < BWD) cnt[tid] = 0;
    if (tid == 0) ovf = 0;
    __syncthreads();
    for (int i = base + tid; i < next; i += 256) atomicAdd(&cnt[packed[i] >> 26], 1);
    __syncthreads();
    const int rc = (tid < BWD) ? cnt[tid] : 0;   // real count
    if (tid == 0) {
        int run = 0;
        for (int j = 0; j < BWD; ++j) { offs[j] = run; run += (cnt[j] + 7) & ~7; }
        if (run > CSRCAP) {  // astronomically unlikely; drop padding
            ovf = 1;
            run = 0;
            for (int j = 0; j < BWD; ++j) { offs[j] = run; run += cnt[j]; }
        }
    }
    __syncthreads();
    const int cbase = b * CSRCAP;
    if (tid < BWD) {
        int node = (b << BSH) + tid;
        if (node < N) {
            int pd = ovf ? rc : ((rc + 7) & ~7);
            int st = cbase + offs[tid];
            rowptr[node] = st;
            pdeg[node] = pd;
            dinv[node] = rsqrtf((float)rc + 1.0f);
            for (int k = rc; k < pd; ++k) col[st + k] = N;  // sentinel -> zero row
        }
        cnt[tid] = offs[tid];  // reuse as in-bucket cursors
    }
    __syncthreads();
    for (int i = base + tid; i < next; i += 256) {
        unsigned int u = packed[i];
        int j = u >> 26;
        int pos = cbase + atomicAdd(&cnt[j], 1);  // LDS atomic only
        col[pos] = (int)(u & 0x03ffffffu);
    }
}

// ---------------------------------------------------------------------------
// MFMA GEMM with LDS-staged W (round-8 proven: 328->277 us total).
// wsw is 32 KB = exactly L1 -> streaming A-rows evict it; staging into LDS
// (XOR swizzle, conflict-free) turns the 8 serial W-legs into LDS reads.
// A-loads issue BEFORE staging so the HBM A-leg hides under staging+barrier.
// Never writes row N (the sentinel zero row survives both layers).
template <bool BF16IN>
__global__ __launch_bounds__(256, 4) void gemm_mfma(const void* __restrict__ Xv,
                                                    const unsigned short* __restrict__ wsw,
                                                    const float* __restrict__ rowscale,
                                                    uint2* __restrict__ Out, int n) {
    __shared__ char sW[32768];
    const int tid = threadIdx.x;
    const int w = tid >> 6;
    const int lane = tid & 63;
    const int q = lane >> 4;
    const int m15 = lane & 15;
    const int rbase = blockIdx.x * 64;

    const int arow = rbase + w * 16 + m15;
    const int srow = (arow < n) ? arow : (n - 1);  // clamped; garbage rows never stored

    // ---- issue A loads first (HBM leg overlaps W staging + barrier) ----
    uint4 ta[4];
    float4 tf[8];
    if (BF16IN) {
        const unsigned short* xr = (const unsigned short*)Xv + (size_t)srow * 128 + q * 8;
        #pragma unroll
        for (int kk = 0; kk < 4; ++kk) ta[kk] = *(const uint4*)(xr + kk * 32);
    } else {
        const float* xr = (const float*)Xv + (size_t)srow * 128 + q * 8;
        #pragma unroll
        for (int kk = 0; kk < 4; ++kk) {
            tf[2 * kk]     = *(const float4*)(xr + kk * 32);
            tf[2 * kk + 1] = *(const float4*)(xr + kk * 32 + 4);
        }
    }

    // ---- stage W into LDS (2048 x 16B, XOR swizzle) ----
    #pragma unroll
    for (int it = 0; it < 8; ++it) {
        int fi = it * 256 + tid;
        uint4 v = ((const uint4*)wsw)[fi];
        *(uint4*)(sW + ((fi * 16) ^ (((fi >> 4) & 7) << 4))) = v;
    }
    __syncthreads();

    // ---- pack A fragments ----
    v8s a[4];
    if (BF16IN) {
        #pragma unroll
        for (int kk = 0; kk < 4; ++kk) a[kk] = __builtin_bit_cast(v8s, ta[kk]);
    } else {
        #pragma unroll
        for (int kk = 0; kk < 4; ++kk) {
            uint4 p;
            p.x = bfpack(tf[2 * kk].x, tf[2 * kk].y);
            p.y = bfpack(tf[2 * kk].z, tf[2 * kk].w);
            p.z = bfpack(tf[2 * kk + 1].x, tf[2 * kk + 1].y);
            p.w = bfpack(tf[2 * kk + 1].z, tf[2 * kk + 1].w);
            a[kk] = __builtin_bit_cast(v8s, p);
        }
    }

    // ---- inner loop: W fragments from LDS (register double-buffer) ----
    const int swz = (m15 & 7) << 4;
    v8s bcur[4], bnxt[4];
    #pragma unroll
    for (int kk = 0; kk < 4; ++kk)
        bcur[kk] = *(const v8s*)(sW + (((m15 * 16 + kk * 4 + q) * 16) ^ swz));

    v4f acc[8];
    #pragma unroll
    for (int nt = 0; nt < 8; ++nt) acc[nt] = (v4f){0.f, 0.f, 0.f, 0.f};

    #pragma unroll
    for (int nt = 0; nt < 8; ++nt) {
        if (nt < 7) {
            #pragma unroll
            for (int kk = 0; kk < 4; ++kk)
                bnxt[kk] = *(const v8s*)(sW +
                    (((((nt + 1) * 16 + m15) * 16 + kk * 4 + q) * 16) ^ swz));
        }
        #pragma unroll
        for (int kk = 0; kk < 4; ++kk)
            acc[nt] = __builtin_amdgcn_mfma_f32_16x16x32_bf16(a[kk], bcur[kk], acc[nt], 0, 0, 0);
        #pragma unroll
        for (int kk = 0; kk < 4; ++kk) bcur[kk] = bnxt[kk];
    }

    // epilogue: D row = q*4+reg, col = nt*16+m15 -> P-order bytes p=m15*8+nt
    #pragma unroll
    for (int reg = 0; reg < 4; ++reg) {
        int row = rbase + w * 16 + q * 4 + reg;
        if (row < n) {
            float sc = rowscale[row];
            unsigned int d0 = fp8x4_enc(acc[0][reg] * sc, acc[1][reg] * sc,
                                        acc[2][reg] * sc, acc[3][reg] * sc);
            unsigned int d1 = fp8x4_enc(acc[4][reg] * sc, acc[5][reg] * sc,
                                        acc[6][reg] * sc, acc[7][reg] * sc);
            Out[(size_t)row * 16 + m15] = make_uint2(d0, d1);
        }
    }
}

// ---------------------------------------------------------------------------
// Fused CSR gather + epilogue on pre-scaled fp8 T' (P-ordered rows):
//   h[d] = relu( (sum_{s in in(d)} T'[s] + T'[d]) * dinv[d] + pbias )
// HALF-wave per dst node (32 lanes x 1 dword = 128 B row) — the round-0
// proven shape (VGPR 28, loads batch-hoisted). CSR is padded to multiples
// of 8 with zero-row sentinels -> per node exactly pdeg/8 (1-3) 8-wide legs.
__global__ __launch_bounds__(256) void gather_fused(const unsigned int* __restrict__ T32,
                                                    const int* __restrict__ rowptr,
                                                    const int* __restrict__ pdeg,
                                                    const int* __restrict__ col,
                                                    const float* __restrict__ dinv,
                                                    const float* __restrict__ pbias,
                                                    uint2* __restrict__ H, int n) {
    const int wave = (blockIdx.x * 256 + threadIdx.x) >> 6;
    const int d = wave * 2 + ((threadIdx.x >> 5) & 1);
    const int hl = threadIdx.x & 31;
    if (d >= n) return;
    int e = rowptr[d];
    const int end = e + pdeg[d];

    v2f sl0 = {0.f, 0.f}, sh0 = {0.f, 0.f}, sl1 = {0.f, 0.f}, sh1 = {0.f, 0.f};

    if ((e & 1) && e < end) {  // never runs on padded CSR (kept for fallback)
        unsigned int u = T32[(size_t)col[e] * 32 + hl];
        sl0 += fp8_dec_lo(u); sh0 += fp8_dec_hi(u);
        ++e;
    }
    for (; e + 7 < end; e += 8) {
        int2 p01 = *(const int2*)(col + e);
        int2 p23 = *(const int2*)(col + e + 2);
        int2 p45 = *(const int2*)(col + e + 4);
        int2 p67 = *(const int2*)(col + e + 6);
        unsigned int u0 = T32[(size_t)p01.x * 32 + hl];
        unsigned int u1 = T32[(size_t)p01.y * 32 + hl];
        unsigned int u2 = T32[(size_t)p23.x * 32 + hl];
        unsigned int u3 = T32[(size_t)p23.y * 32 + hl];
        unsigned int u4 = T32[(size_t)p45.x * 32 + hl];
        unsigned int u5 = T32[(size_t)p45.y * 32 + hl];
        unsigned int u6 = T32[(size_t)p67.x * 32 + hl];
        unsigned int u7 = T32[(size_t)p67.y * 32 + hl];
        sl0 += fp8_dec_lo(u0); sh0 += fp8_dec_hi(u0);
        sl1 += fp8_dec_lo(u1); sh1 += fp8_dec_hi(u1);
        sl0 += fp8_dec_lo(u2); sh0 += fp8_dec_hi(u2);
        sl1 += fp8_dec_lo(u3); sh1 += fp8_dec_hi(u3);
        sl0 += fp8_dec_lo(u4); sh0 += fp8_dec_hi(u4);
        sl1 += fp8_dec_lo(u5); sh1 += fp8_dec_hi(u5);
        sl0 += fp8_dec_lo(u6); sh0 += fp8_dec_hi(u6);
        sl1 += fp8_dec_lo(u7); sh1 += fp8_dec_hi(u7);
    }
    for (; e + 1 < end; e += 2) {  // never runs on padded CSR
        int2 p = *(const int2*)(col + e);
        unsigned int u0 = T32[(size_t)p.x * 32 + hl];
        unsigned int u1 = T32[(size_t)p.y * 32 + hl];
        sl0 += fp8_dec_lo(u0); sh0 += fp8_dec_hi(u0);
        sl1 += fp8_dec_lo(u1); sh1 += fp8_dec_hi(u1);
    }
    if (e < end) {                 // never runs on padded CSR
        unsigned int u = T32[(size_t)col[e] * 32 + hl];
        sl0 += fp8_dec_lo(u); sh0 += fp8_dec_hi(u);
    }

    // self term
    unsigned int su = T32[(size_t)d * 32 + hl];
    sl0 += fp8_dec_lo(su); sh0 += fp8_dec_hi(su);
    v2f sl = sl0 + sl1, sh = sh0 + sh1;

    const float di = dinv[d];
    const float4 bv = ((const float4*)pbias)[hl];
    float o0 = fmaxf(fmaf(sl.x, di, bv.x), 0.f);
    float o1 = fmaxf(fmaf(sl.y, di, bv.y), 0.f);
    float o2 = fmaxf(fmaf(sh.x, di, bv.z), 0.f);
    float o3 = fmaxf(fmaf(sh.y, di, bv.w), 0.f);
    uint2 o;
    o.x = bfpack(o0, o1);
    o.y = bfpack(o2, o3);
    H[(size_t)d * 32 + hl] = o;
}

// ---------------------------------------------------------------------------
// Layer-2 gather with fused mean-pool at 64-node granularity (round-9 proven:
// 277->263 us). NO device-scope fences here — round 10 showed one
// __threadfence per block invalidates the per-XCD L2s and destroys the
// LLC/L2-resident T' working set (gather 36->212 us). Heads stay in their
// own tiny kernel.
__global__ __launch_bounds__(256) void gather_pool(const unsigned int* __restrict__ T32,
                                                   const int* __restrict__ rowptr,
                                                   const int* __restrict__ pdeg,
                                                   const int* __restrict__ col,
                                                   const float* __restrict__ dinv,
                                                   const float* __restrict__ pbias,
                                                   float* __restrict__ pooled,
                                                   const int* __restrict__ batch,
                                                   int n) {
    __shared__ float pacc[256];   // [2 graph slots][128 dims]
    const int tid = threadIdx.x;
    const int hw = tid >> 5;      // half-wave 0..7
    const int hl = tid & 31;
    const int base = blockIdx.x * 64;
    pacc[tid] = 0.f;
    const int g0 = batch[base < n ? base : (n - 1)];
    __syncthreads();

    const float4 bv = ((const float4*)pbias)[hl];
    float r0a = 0.f, r0b = 0.f, r0c = 0.f, r0d = 0.f;   // graph slot 0
    float r1a = 0.f, r1b = 0.f, r1c = 0.f, r1d = 0.f;   // graph slot 1

    for (int it = 0; it < 8; ++it) {
        const int d = base + hw * 8 + it;   // 8 consecutive nodes per half-wave
        if (d < n) {
            int e = rowptr[d];
            const int end = e + pdeg[d];

            v2f sl0 = {0.f, 0.f}, sh0 = {0.f, 0.f}, sl1 = {0.f, 0.f}, sh1 = {0.f, 0.f};

            if ((e & 1) && e < end) {  // never runs on padded CSR (fallback only)
                unsigned int u = T32[(size_t)col[e] * 32 + hl];
                sl0 += fp8_dec_lo(u); sh0 += fp8_dec_hi(u);
                ++e;
            }
            for (; e + 7 < end; e += 8) {
                int2 p01 = *(const int2*)(col + e);
                int2 p23 = *(const int2*)(col + e + 2);
                int2 p45 = *(const int2*)(col + e + 4);
                int2 p67 = *(const int2*)(col + e + 6);
                unsigned int u0 = T32[(size_t)p01.x * 32 + hl];
                unsigned int u1 = T32[(size_t)p01.y * 32 + hl];
                unsigned int u2 = T32[(size_t)p23.x * 32 + hl];
                unsigned int u3 = T32[(size_t)p23.y * 32 + hl];
                unsigned int u4 = T32[(size_t)p45.x * 32 + hl];
                unsigned int u5 = T32[(size_t)p45.y * 32 + hl];
                unsigned int u6 = T32[(size_t)p67.x * 32 + hl];
                unsigned int u7 = T32[(size_t)p67.y * 32 + hl];
                sl0 += fp8_dec_lo(u0); sh0 += fp8_dec_hi(u0);
                sl1 += fp8_dec_lo(u1); sh1 += fp8_dec_hi(u1);
                sl0 += fp8_dec_lo(u2); sh0 += fp8_dec_hi(u2);
                sl1 += fp8_dec_lo(u3); sh1 += fp8_dec_hi(u3);
                sl0 += fp8_dec_lo(u4); sh0 += fp8_dec_hi(u4);
                sl1 += fp8_dec_lo(u5); sh1 += fp8_dec_hi(u5);
                sl0 += fp8_dec_lo(u6); sh0 += fp8_dec_hi(u6);
                sl1 += fp8_dec_lo(u7); sh1 += fp8_dec_hi(u7);
            }
            for (; e + 1 < end; e += 2) {  // fallback only
                int2 p = *(const int2*)(col + e);
                unsigned int u0 = T32[(size_t)p.x * 32 + hl];
                unsigned int u1 = T32[(size_t)p.y * 32 + hl];
                sl0 += fp8_dec_lo(u0); sh0 += fp8_dec_hi(u0);
                sl1 += fp8_dec_lo(u1); sh1 += fp8_dec_hi(u1);
            }
            if (e < end) {                 // fallback only
                unsigned int u = T32[(size_t)col[e] * 32 + hl];
                sl0 += fp8_dec_lo(u); sh0 += fp8_dec_hi(u);
            }

            unsigned int su = T32[(size_t)d * 32 + hl];  // self term
            sl0 += fp8_dec_lo(su); sh0 += fp8_dec_hi(su);
            v2f sl = sl0 + sl1, sh = sh0 + sh1;

            const float di = dinv[d];
            float o0 = fmaxf(fmaf(sl.x, di, bv.x), 0.f);
            float o1 = fmaxf(fmaf(sl.y, di, bv.y), 0.f);
            float o2 = fmaxf(fmaf(sh.x, di, bv.z), 0.f);
            float o3 = fmaxf(fmaf(sh.y, di, bv.w), 0.f);

            const int gi = batch[d] - g0;
            if (gi == 0) {
                r0a += o0; r0b += o1; r0c += o2; r0d += o3;
            } else if (gi == 1) {
                r1a += o0; r1b += o1; r1c += o2; r1d += o3;
            } else {  // >2 graphs in a 64-node window: ~impossible, stay correct
                atomicAdd(&pooled[(size_t)(g0 + gi) * 128 + 4 * hl + 0], o0);
                atomicAdd(&pooled[(size_t)(g0 + gi) * 128 + 4 * hl + 1], o1);
                atomicAdd(&pooled[(size_t)(g0 + gi) * 128 + 4 * hl + 2], o2);
                atomicAdd(&pooled[(size_t)(g0 + gi) * 128 + 4 * hl + 3], o3);
            }
        }
    }

    // reduce the 8 half-waves' register partials in LDS
    atomicAdd(&pacc[4 * hl + 0], r0a);
    atomicAdd(&pacc[4 * hl + 1], r0b);
    atomicAdd(&pacc[4 * hl + 2], r0c);
    atomicAdd(&pacc[4 * hl + 3], r0d);
    if (r1a != 0.f || r1b != 0.f || r1c != 0.f || r1d != 0.f) {
        atomicAdd(&pacc[128 + 4 * hl + 0], r1a);
        atomicAdd(&pacc[128 + 4 * hl + 1], r1b);
        atomicAdd(&pacc[128 + 4 * hl + 2], r1c);
        atomicAdd(&pacc[128 + 4 * hl + 3], r1d);
    }
    __syncthreads();
    float v = pacc[tid];
    if (v != 0.f) {               // slot-1 mostly all-zero; also guards g0+1>=G
        int gg = g0 + (tid >> 7);
        atomicAdd(&pooled[(size_t)gg * 128 + (tid & 127)], v);
    }
}

// ---------------------------------------------------------------------------
// out layout: [G*A action_mean][A std][G value]. pooled is P-ordered ->
// index head weights by c(p).
__global__ void head_kernel(const float* __restrict__ pooled, const int* __restrict__ gstart,
                            const float* __restrict__ Wa, const float* __restrict__ ba,
                            const float* __restrict__ Wv, const float* __restrict__ bv,
                            const float* __restrict__ log_std, float* __restrict__ out, int G) {
    int g = blockIdx.x;
    int t = threadIdx.x;  // 64
    __shared__ float sp[128];
    float inv = 1.0f / fmaxf((float)(gstart[g + 1] - gstart[g]), 1.0f);
    sp[t] = pooled[(size_t)g * 128 + t] * inv;
    sp[t + 64] = pooled[(size_t)g * 128 + 64 + t] * inv;
    __syncthreads();
    if (t < 32) {
        float s = 0.f;
        #pragma unroll 8
        for (int k = 0; k < 128; ++k) s = fmaf(sp[k], Wa[CP(k) * ADIM + t], s);
        out[g * ADIM + t] = s + ba[t];
        if (g == 0) out[G * ADIM + t] = expf(log_std[t]);
    } else if (t == 32) {
        float s = 0.f;
        #pragma unroll 8
        for (int k = 0; k < 128; ++k) s = fmaf(sp[k], Wv[CP(k)], s);
        out[G * ADIM + ADIM + g] = s + bv[0];
    }
}

// ---------------------------------------------------------------------------
extern "C" void kernel_launch(void* const* d_in, const int* in_sizes, int n_in,
                              void* d_out, int out_size, void* d_ws, size_t ws_size,
                              hipStream_t stream) {
    const float* x       = (const float*)d_in[0];
    const int*   ei      = (const int*)d_in[1];
    const int*   batch   = (const int*)d_in[2];
    const float* W1      = (const float*)d_in[3];
    const float* b1      = (const float*)d_in[4];
    const float* W2      = (const float*)d_in[5];
    const float* b2      = (const float*)d_in[6];
    const float* Wa      = (const float*)d_in[7];
    const float* ba      = (const float*)d_in[8];
    const float* Wv      = (const float*)d_in[9];
    const float* bv      = (const float*)d_in[10];
    const float* log_std = (const float*)d_in[11];
    float* out = (float*)d_out;

    const int N = in_sizes[0] / FDIM;
    const int E = in_sizes[1] / 2;
    const int G = (out_size - ADIM) / (ADIM + 1);
    const int NB = (N + BWD - 1) >> BSH;          // buckets (<= MAXNB for N <= 131072)
    const int NBLK = (E + CHUNK - 1) / CHUNK;     // binning blocks
    const int M = NB * NBLK;                      // scan length
    const int nscanA = (M + 2047) / 2048;         // <= 256

    const int* src = ei;
    const int* dst = ei + E;

    auto align = [](size_t v) { return (v + 255) & ~(size_t)255; };
    char* ws = (char*)d_ws;
    size_t off = 0;
    int*   hist   = (int*)(ws + off);   off = align(off + (size_t)M * 4);
    int*   excl   = (int*)(ws + off);   off = align(off + (size_t)M * 4);
    int*   bsum   = (int*)(ws + off);   off = align(off + (size_t)256 * 4);
    int*   rowptr = (int*)(ws + off);   off = align(off + (size_t)(N + 1) * 4);
    int*   pdeg   = (int*)(ws + off);   off = align(off + (size_t)N * 4);
    int*   gstart = (int*)(ws + off);   off = align(off + (size_t)(G + 1) * 4);
    float* dinv   = (float*)(ws + off); off = align(off + (size_t)N * 4);
    float* pooled = (float*)(ws + off); off = align(off + (size_t)G * HDIM * 4);
    unsigned short* wsw1 = (unsigned short*)(ws + off); off = align(off + (size_t)16384 * 2);
    unsigned short* wsw2 = (unsigned short*)(ws + off); off = align(off + (size_t)16384 * 2);
    float* pb1    = (float*)(ws + off); off = align(off + (size_t)128 * 4);
    float* pb2    = (float*)(ws + off); off = align(off + (size_t)128 * 4);
    unsigned int* packed = (unsigned int*)(ws + off); off = align(off + (size_t)E * 4);
    int*   col    = (int*)(ws + off);   off = align(off + (size_t)NB * CSRCAP * 4);  // padded CSR
    unsigned int* bufA = (unsigned int*)(ws + off); off = align(off + (size_t)(N + 1) * 32 * 4);  // fp8 (N+1)x128; row N = zeros
    unsigned int* bufB = (unsigned int*)(ws + off); off = align(off + (size_t)N * 64 * 4);  // bf16 N x 128 (P-order)
    (void)ws_size;

    unsigned int* zrow = bufA + (size_t)N * 32;

    const int blkGemm = (N + 63) / 64;
    const int blkGather = (N + 7) / 8;            // half-wave per node, 8 nodes/block
    const int blkGP = (N + 63) / 64;              // 64 nodes per gather_pool block

    // ---- binning -> padded CSR + dinv (no global atomics); setup fused in ----
    block_hist_setup<<<NBLK + 3, 256, 0, stream>>>(dst, hist, E, NB, NBLK,
                                                   W1, W2, b1, b2, wsw1, wsw2, pb1, pb2,
                                                   batch, gstart, pooled, zrow, N, G);
    scanA<<<nscanA, 256, 0, stream>>>(hist, excl, bsum, M, NB, NBLK);
    bucket_scatter<<<NBLK, 256, 0, stream>>>(src, dst, excl, bsum, packed, E, NB, NBLK, nscanA);
    bucket_to_csr<<<NB, 256, 0, stream>>>(packed, excl, bsum, rowptr, pdeg, dinv, col,
                                          E, N, NB, NBLK, nscanA);

    // ---- layer 1 (fp32 in, fp8 P-order out) ----
    gemm_mfma<false><<<blkGemm, 256, 0, stream>>>(x, wsw1, dinv, (uint2*)bufA, N);
    gather_fused<<<blkGather, 256, 0, stream>>>(bufA, rowptr, pdeg, col, dinv, pb1,
                                                (uint2*)bufB, N);

    // ---- layer 2 (bf16 P-order in, fp8 P-order out) + fused mean-pool ----
    gemm_mfma<true><<<blkGemm, 256, 0, stream>>>(bufB, wsw2, dinv, (uint2*)bufA, N);
    gather_pool<<<blkGP, 256, 0, stream>>>(bufA, rowptr, pdeg, col, dinv, pb2,
                                           pooled, batch, N);

    // ---- heads ----
    head_kernel<<<G, 64, 0, stream>>>(pooled, gstart, Wa, ba, Wv, bv, log_std, out, G);
}